// Round 1
// baseline (358.147 us; speedup 1.0000x reference)
//
#include <hip/hip_runtime.h>
#include <hip/hip_bf16.h>

// Problem constants
#define DIM   512
#define NTR   16384
#define NT    8192
#define NCLS  16
#define NROWS (NTR + NT)   // 24576 projection rows

// Main-kernel tiling
#define JCHUNK 512                 // train points per block
#define NJ     (NTR / JCHUNK)      // 32 j-chunks
#define IBLK   256                 // test points per block (1 per thread)
#define NIB    (NT / IBLK)         // 32 i-blocks

// ws layout (floats):
//   [0, 49152)        kq: [24576][2]; rows [0,NTR)=k (train), [NTR,NROWS)=q (test)
//   [49152, 180224)   numer [8192][16]
//   [180224, 188416)  denom [8192]
#define WS_KQ_F    (NROWS * 2)           // 49152
#define WS_NUMER_F (NT * NCLS)           // 131072
#define WS_DENOM_F (NT)                  // 8192

// ---------------------------------------------------------------------------
// Kernel 1: fused projection. One wave per row (512-dim dot with A's 2 cols).
// Rows [0,NTR) come from xtr, rows [NTR,NROWS) from xt. Memory-bound: 48 MB.
// ---------------------------------------------------------------------------
__global__ __launch_bounds__(256) void proj_kernel(
    const float* __restrict__ xtr, const float* __restrict__ xt,
    const float* __restrict__ A, float* __restrict__ kq)
{
    const int wave = threadIdx.x >> 6;
    const int lane = threadIdx.x & 63;
    const int row  = blockIdx.x * 4 + wave;

    const float* x = (row < NTR) ? (xtr + (size_t)row * DIM)
                                 : (xt + (size_t)(row - NTR) * DIM);
    float a0 = 0.f, a1 = 0.f;
#pragma unroll
    for (int t = 0; t < 2; ++t) {
        const int d = lane * 4 + t * 256;          // coalesced float4 across lanes
        float4 xv = *(const float4*)(x + d);
        float4 A0 = *(const float4*)(A + 2 * d);       // A[d..d+1][0..1]
        float4 A1 = *(const float4*)(A + 2 * d + 4);   // A[d+2..d+3][0..1]
        a0 += xv.x * A0.x + xv.y * A0.z + xv.z * A1.x + xv.w * A1.z;
        a1 += xv.x * A0.y + xv.y * A0.w + xv.z * A1.y + xv.w * A1.w;
    }
    // 64-lane butterfly reduction
#pragma unroll
    for (int off = 32; off >= 1; off >>= 1) {
        a0 += __shfl_xor(a0, off, 64);
        a1 += __shfl_xor(a1, off, 64);
    }
    if (lane == 0) {
        kq[row * 2 + 0] = a0;
        kq[row * 2 + 1] = a1;
    }
}

// ---------------------------------------------------------------------------
// Kernel 2: main. Grid (NIB, NJ). Each thread owns one test point i and
// accumulates exp(q_i . k_j) * ytr[j][:] plus the denominator over its
// block's 512-train-point chunk. k and ytr chunk staged in LDS; all lanes
// step j together -> LDS reads are same-address broadcasts (conflict-free).
// Partials flushed with atomicAdd (32 writers per address).
// ---------------------------------------------------------------------------
__global__ __launch_bounds__(256) void simmain_kernel(
    const float* __restrict__ kq, const float* __restrict__ ytr,
    float* __restrict__ numer, float* __restrict__ denom)
{
    __shared__ float k0s[JCHUNK];
    __shared__ float k1s[JCHUNK];
    __shared__ float ys[JCHUNK * NCLS];   // 32 KB

    const int tid = threadIdx.x;
    const int i   = blockIdx.x * IBLK + tid;
    const int j0  = blockIdx.y * JCHUNK;

    // Stage k chunk (512 x 2 floats)
    for (int r = tid; r < JCHUNK; r += 256) {
        float2 kv = *(const float2*)(kq + 2 * (j0 + r));
        k0s[r] = kv.x;
        k1s[r] = kv.y;
    }
    // Stage ytr chunk (512 x 16 floats = 32 KB), linear float4 copy
    {
        const float4* ysrc = (const float4*)(ytr + (size_t)j0 * NCLS);
        float4* ydst = (float4*)ys;
#pragma unroll
        for (int p = 0; p < (JCHUNK * NCLS / 4) / 256; ++p)
            ydst[tid + 256 * p] = ysrc[tid + 256 * p];
    }
    __syncthreads();

    const float q0 = kq[2 * (NTR + i) + 0];
    const float q1 = kq[2 * (NTR + i) + 1];

    float acc[NCLS];
#pragma unroll
    for (int c = 0; c < NCLS; ++c) acc[c] = 0.f;
    float dsum = 0.f;

#pragma unroll 4
    for (int jj = 0; jj < JCHUNK; ++jj) {
        const float s = q0 * k0s[jj] + q1 * k1s[jj];
        const float e = __expf(s);       // logits bounded (~|11| max): no max-sub needed
        dsum += e;
        const float4* y = (const float4*)(ys + jj * NCLS);
        float4 y0 = y[0], y1 = y[1], y2 = y[2], y3 = y[3];
        acc[0]  += e * y0.x; acc[1]  += e * y0.y; acc[2]  += e * y0.z; acc[3]  += e * y0.w;
        acc[4]  += e * y1.x; acc[5]  += e * y1.y; acc[6]  += e * y1.z; acc[7]  += e * y1.w;
        acc[8]  += e * y2.x; acc[9]  += e * y2.y; acc[10] += e * y2.z; acc[11] += e * y2.w;
        acc[12] += e * y3.x; acc[13] += e * y3.y; acc[14] += e * y3.z; acc[15] += e * y3.w;
    }

#pragma unroll
    for (int c = 0; c < NCLS; ++c)
        atomicAdd(&numer[(size_t)i * NCLS + c], acc[c]);
    atomicAdd(&denom[i], dsum);
}

// ---------------------------------------------------------------------------
// Kernel 3: finalize — divide numerators by softmax denominator.
// ---------------------------------------------------------------------------
__global__ __launch_bounds__(256) void finalize_kernel(
    const float* __restrict__ numer, const float* __restrict__ denom,
    float* __restrict__ out)
{
    const int idx = blockIdx.x * 256 + threadIdx.x;   // < NT*NCLS
    out[idx] = numer[idx] / denom[idx >> 4];
}

// ---------------------------------------------------------------------------
extern "C" void kernel_launch(void* const* d_in, const int* in_sizes, int n_in,
                              void* d_out, int out_size, void* d_ws, size_t ws_size,
                              hipStream_t stream)
{
    const float* xtr = (const float*)d_in[0];   // [16384][512]
    const float* ytr = (const float*)d_in[1];   // [16384][16]
    const float* xt  = (const float*)d_in[2];   // [8192][512]
    const float* A   = (const float*)d_in[3];   // [512][2]
    float* out = (float*)d_out;                 // [8192][16]

    float* kq    = (float*)d_ws;                // 49152 floats
    float* numer = kq + WS_KQ_F;                // 131072 floats
    float* denom = numer + WS_NUMER_F;          // 8192 floats

    // ws is poisoned 0xAA before every call: zero the accumulators.
    hipMemsetAsync(numer, 0, (WS_NUMER_F + WS_DENOM_F) * sizeof(float), stream);

    proj_kernel<<<NROWS / 4, 256, 0, stream>>>(xtr, xt, A, kq);
    simmain_kernel<<<dim3(NIB, NJ), 256, 0, stream>>>(kq, ytr, numer, denom);
    finalize_kernel<<<(NT * NCLS) / 256, 256, 0, stream>>>(numer, denom, out);
}